// Round 6
// baseline (149.172 us; speedup 1.0000x reference)
//
#include <hip/hip_runtime.h>
#include <math.h>

#define NPROP 2048
#define NCLS 81
#define NFG 80
#define NBLK 80        // one block per fg class; all co-resident (<< 256 CUs)
#define CAP 512        // per-class candidate cap (mean ~59, huge margin)
#define TOPC 100       // per-class survivors that can matter for global top-100
#define CPAD 16        // ints per counter (64B cacheline padding)
#define NB 1152        // score histogram buckets
#define BMIN 0x7A99    // bits(0.05f) >> 15

// ws layout:
//   ccnt : int[80*16]   @ 0       (5120 B, zeroed via memsetAsync)
//   bar  : int[16]      @ 5120    (zeroed via memsetAsync)
//   scnt : int[80]      @ 5184    (fully written in phase C)
//   cand : ull[80*512]  @ 5504
//   surv : ull[80*512]  @ 333184  (end 660864)

#define LDS_FENCE() do { __builtin_amdgcn_wave_barrier(); \
    asm volatile("s_waitcnt lgkmcnt(0)" ::: "memory");     \
    __builtin_amdgcn_wave_barrier(); } while (0)

__device__ __forceinline__ void grid_arrive(int* bar) {
    __syncthreads();                 // whole block done with prior phase
    if (threadIdx.x == 0) {
        __threadfence();             // publish writes device-wide
        atomicAdd(bar, 1);           // device-scope by default
    }
}

__device__ __forceinline__ void grid_wait(const int* bar, int target) {
    if (threadIdx.x == 0) {
        int guard = 0;
        while (__hip_atomic_load(bar, __ATOMIC_ACQUIRE,
                                 __HIP_MEMORY_SCOPE_AGENT) < target) {
            if (++guard > (1 << 24)) break;   // safety: never hang the replay
        }
    }
    __syncthreads();
    __threadfence();                 // invalidate caches before reading peers' data
}

__device__ __forceinline__ void decode_clip(const float* __restrict__ props,
                                            const float* __restrict__ reg,
                                            int p, int cls, float out[4]) {
    float px1 = props[p * 4 + 0], py1 = props[p * 4 + 1];
    float px2 = props[p * 4 + 2], py2 = props[p * 4 + 3];
    float w = px2 - px1 + 1.0f;
    float h = py2 - py1 + 1.0f;
    float cx = px1 + 0.5f * w;
    float cy = py1 + 0.5f * h;
    const float* r = reg + (size_t)p * (NCLS * 4) + cls * 4;
    float dx = r[0] / 10.0f;
    float dy = r[1] / 10.0f;
    float dw = fminf(r[2] / 5.0f, 4.135166556742356f);
    float dh = fminf(r[3] / 5.0f, 4.135166556742356f);
    float pcx = dx * w + cx;
    float pcy = dy * h + cy;
    float pw = expf(dw) * w;
    float ph = expf(dh) * h;
    float x1 = pcx - 0.5f * pw;
    float y1 = pcy - 0.5f * ph;
    float x2 = pcx + 0.5f * pw - 1.0f;
    float y2 = pcy + 0.5f * ph - 1.0f;
    out[0] = fminf(fmaxf(x1, 0.0f), 1332.0f);
    out[1] = fminf(fmaxf(y1, 0.0f), 799.0f);
    out[2] = fminf(fmaxf(x2, 0.0f), 1332.0f);
    out[3] = fminf(fmaxf(y2, 0.0f), 799.0f);
}

__global__ __launch_bounds__(256) void fused_postproc(const float* __restrict__ logits,
                                                      const float* __restrict__ reg,
                                                      const float* __restrict__ props,
                                                      int* __restrict__ ccnt,
                                                      int* __restrict__ bar,
                                                      int* __restrict__ scnt,
                                                      unsigned long long* __restrict__ cand,
                                                      unsigned long long* __restrict__ surv,
                                                      float* __restrict__ out) {
    const int tid = threadIdx.x;
    const int lane = tid & 63;
    const int bw = tid >> 6;

    // LDS: NMS arrays (phase C) + topk arrays (phase E, block 0 only)
    __shared__ unsigned long long keys[CAP];   // 4096 B
    __shared__ float4 bxs[CAP];                // 8192 B
    __shared__ unsigned int hist[NB];          // 4608 B
    __shared__ unsigned long long comp[1024];  // 8192 B
    __shared__ int s_n[NFG];
    __shared__ int sB;
    __shared__ int compN;

    // ---------------- Phase A: softmax + candidate scatter ----------------
    for (int row = blockIdx.x * 4 + bw; row < NPROP; row += NBLK * 4) {
        const float* lrow = logits + (size_t)row * NCLS;
        float a = lrow[lane];                  // lane < 64 < 81
        bool hasb = (lane + 64) < NCLS;        // lanes 0..16
        float b = hasb ? lrow[lane + 64] : -INFINITY;
        float m = fmaxf(a, b);
        #pragma unroll
        for (int s = 32; s; s >>= 1) m = fmaxf(m, __shfl_xor(m, s));
        float ea = expf(a - m);
        float eb = hasb ? expf(b - m) : 0.0f;
        float sum = ea + eb;
        #pragma unroll
        for (int s = 32; s; s >>= 1) sum += __shfl_xor(sum, s);
        float pa = ea / sum;
        float pb = eb / sum;
        unsigned int np = (unsigned int)(~row);
        if (lane != 0 && pa > 0.05f) {         // skip background class 0
            int c = lane - 1;
            int pos = atomicAdd(&ccnt[c * CPAD], 1);
            if (pos < CAP)
                cand[c * CAP + pos] =
                    ((unsigned long long)__float_as_uint(pa) << 32) | np;
        }
        if (hasb && pb > 0.05f) {              // classes 64..80 -> c = 63..79
            int c = lane + 63;
            int pos = atomicAdd(&ccnt[c * CPAD], 1);
            if (pos < CAP)
                cand[c * CAP + pos] =
                    ((unsigned long long)__float_as_uint(pb) << 32) | np;
        }
    }

    // ---------------- Barrier 1: all scatters visible ----------------
    grid_arrive(bar);
    grid_wait(bar, NBLK);

    // ---------------- Phase C: per-class NMS (wave 0 of each block) --------
    const int c = blockIdx.x;
    if (bw == 0) {
        int M = ccnt[c * CPAD];
        if (M > CAP) M = CAP;
        if (M > 0) {
            int S = 64;
            while (S < M) S <<= 1;
            for (int i = lane; i < S; i += 64)
                keys[i] = (i < M) ? cand[c * CAP + i] : 0ULL;
            LDS_FENCE();

            // wave-synchronous bitonic sort descending (pads sink to back)
            for (int k = 2; k <= S; k <<= 1) {
                for (int j = k >> 1; j > 0; j >>= 1) {
                    for (int i = lane; i < S; i += 64) {
                        int l = i ^ j;
                        if (l > i) {
                            unsigned long long A = keys[i], B = keys[l];
                            bool dir = ((i & k) == 0);
                            if ((A < B) == dir) { keys[i] = B; keys[l] = A; }
                        }
                    }
                    LDS_FENCE();
                }
            }

            // decode boxes: own slots to registers, all to LDS for broadcast
            float4 myb[8];
            #pragma unroll
            for (int ns = 0; ns < 8; ++ns) {
                int idx = lane + ns * 64;
                if (idx < M) {
                    unsigned long long key = keys[idx];
                    int p = (int)(~(unsigned int)key);
                    float b4[4];
                    decode_clip(props, reg, p, c + 1, b4);
                    float4 f = make_float4(b4[0], b4[1], b4[2], b4[3]);
                    myb[ns] = f;
                    bxs[idx] = f;
                }
            }
            LDS_FENCE();

            // greedy NMS: sequential i, suppression bits in registers
            unsigned int my_sup = 0u;
            for (int i = 0; i < M; ++i) {
                int owner = i & 63, slot = i >> 6;
                unsigned int os = __shfl(my_sup, owner);
                if ((os >> slot) & 1u) continue;   // wave-uniform
                float4 bi = bxs[i];                // broadcast LDS read
                float ai = (bi.z - bi.x + 1.0f) * (bi.w - bi.y + 1.0f);
                #pragma unroll
                for (int ns = 0; ns < 8; ++ns) {
                    int j = lane + ns * 64;
                    if (j < M && j > i) {
                        float4 bj = myb[ns];
                        float aj = (bj.z - bj.x + 1.0f) * (bj.w - bj.y + 1.0f);
                        float ltx = fmaxf(bi.x, bj.x), lty = fmaxf(bi.y, bj.y);
                        float rbx = fminf(bi.z, bj.z), rby = fminf(bi.w, bj.w);
                        float iw = fmaxf(rbx - ltx + 1.0f, 0.0f);
                        float ih = fmaxf(rby - lty + 1.0f, 0.0f);
                        float inter = iw * ih;
                        float iou = inter / (ai + aj - inter);
                        if (iou > 0.5f) my_sup |= (1u << ns);
                    }
                }
            }

            // ballot-compact survivors (descending order), re-key with ~flat
            int base = 0;
            #pragma unroll
            for (int ns = 0; ns < 8; ++ns) {
                if (ns * 64 >= M) break;           // uniform
                int j = lane + ns * 64;
                bool keep = (j < M) && !((my_sup >> ns) & 1u);
                unsigned long long mask = __ballot(keep);
                if (keep) {
                    int pos = base + __popcll(mask & ((1ULL << lane) - 1ULL));
                    unsigned long long key = keys[j];
                    int p = (int)(~(unsigned int)key);
                    unsigned int flat = (unsigned int)(c * NPROP + p);
                    surv[c * CAP + pos] =
                        (key & 0xFFFFFFFF00000000ULL) | (unsigned int)(~flat);
                }
                base += __popcll(mask);
            }
            if (lane == 0) scnt[c] = base;
        } else {
            if (lane == 0) scnt[c] = 0;
        }
    }

    // ---------------- Barrier 2: survivors visible; only block 0 waits -----
    grid_arrive(bar);
    if (blockIdx.x != 0) return;
    grid_wait(bar, 2 * NBLK);

    // ---------------- Phase E: radix-select top-100 (block 0) --------------
    for (int i = tid; i < NB; i += 256) hist[i] = 0u;
    if (tid < NFG) {
        int k = scnt[tid];
        s_n[tid] = (k > TOPC) ? TOPC : k;
    }
    if (tid == 0) compN = 0;
    __syncthreads();

    for (int idx = tid; idx < NFG * TOPC; idx += 256) {
        int cc = idx / TOPC, i = idx - cc * TOPC;
        if (i < s_n[cc]) {
            unsigned long long key = surv[cc * CAP + i];
            int b = (int)(((unsigned int)(key >> 32)) >> 15) - BMIN;
            b = b < 0 ? 0 : (b >= NB ? NB - 1 : b);
            atomicAdd(&hist[b], 1u);
        }
    }
    __syncthreads();

    // wave 0: suffix-sum from top to find threshold bucket (cum >= 100)
    if (tid < 64) {
        int running = 0, Bstar = 0;
        bool found = false;
        for (int chunk = NB - 64; chunk >= 0; chunk -= 64) {
            int b = chunk + 63 - tid;              // lane 0 = highest bucket
            int s = (int)hist[b];
            #pragma unroll
            for (int d = 1; d < 64; d <<= 1) {
                int o = __shfl_up(s, d);
                if (tid >= d) s += o;
            }
            int cum = running + s;
            unsigned long long m = __ballot(cum >= TOPC);
            if (m != 0ULL) {
                int l = (int)__ffsll((unsigned long long)m) - 1;
                Bstar = chunk + 63 - l;
                found = true;
                break;
            }
            running += __shfl(s, 63);
        }
        if (!found) Bstar = 0;
        if (tid == 0) sB = Bstar;
    }
    __syncthreads();
    int Bstar = sB;

    // compact candidates with bucket >= Bstar
    for (int idx = tid; idx < NFG * TOPC; idx += 256) {
        int cc = idx / TOPC, i = idx - cc * TOPC;
        if (i < s_n[cc]) {
            unsigned long long key = surv[cc * CAP + i];
            int b = (int)(((unsigned int)(key >> 32)) >> 15) - BMIN;
            b = b < 0 ? 0 : (b >= NB ? NB - 1 : b);
            if (b >= Bstar) {
                int pos = atomicAdd(&compN, 1);
                if (pos < 1024) comp[pos] = key;
            }
        }
    }
    __syncthreads();
    int K = compN;
    if (K > 1024) K = 1024;
    int P = 128;
    while (P < K) P <<= 1;
    for (int i = K + tid; i < P; i += 256) comp[i] = 0ULL;
    __syncthreads();

    // wave 0: wave-synchronous bitonic sort descending over comp[0..P)
    if (tid < 64) {
        for (int k = 2; k <= P; k <<= 1) {
            for (int j = k >> 1; j > 0; j >>= 1) {
                for (int i = tid; i < P; i += 64) {
                    int l = i ^ j;
                    if (l > i) {
                        unsigned long long A = comp[i], B = comp[l];
                        bool dir = ((i & k) == 0);
                        if ((A < B) == dir) { comp[i] = B; comp[l] = A; }
                    }
                }
                LDS_FENCE();
            }
        }
    }
    __syncthreads();

    if (tid < TOPC) {
        unsigned long long key = comp[tid];
        float score;
        int flat;
        if (key == 0ULL) {             // < 100 total survivors: not expected
            score = -1.0f;
            flat = tid;
        } else {
            score = __uint_as_float((unsigned int)(key >> 32));
            flat = (int)(~(unsigned int)key);
        }
        int cc = flat >> 11;           // NPROP = 2^11
        int p = flat & (NPROP - 1);
        float b4[4];
        decode_clip(props, reg, p, cc + 1, b4);
        out[tid * 4 + 0] = b4[0];
        out[tid * 4 + 1] = b4[1];
        out[tid * 4 + 2] = b4[2];
        out[tid * 4 + 3] = b4[3];
        out[400 + tid] = score;
        out[500 + tid] = (float)(cc + 1);
    }
}

extern "C" void kernel_launch(void* const* d_in, const int* in_sizes, int n_in,
                              void* d_out, int out_size, void* d_ws, size_t ws_size,
                              hipStream_t stream) {
    const float* logits = (const float*)d_in[0];
    const float* reg    = (const float*)d_in[1];
    const float* props  = (const float*)d_in[2];
    float* out = (float*)d_out;

    int* ccnt = (int*)d_ws;
    int* bar  = (int*)((char*)d_ws + 5120);
    int* scnt = (int*)((char*)d_ws + 5184);
    unsigned long long* cand = (unsigned long long*)((char*)d_ws + 5504);
    unsigned long long* surv = (unsigned long long*)((char*)d_ws + 333184);

    hipMemsetAsync(d_ws, 0, 5184, stream);
    hipLaunchKernelGGL(fused_postproc, dim3(NBLK), dim3(256), 0, stream,
                       logits, reg, props, ccnt, bar, scnt, cand, surv, out);
}

// Round 7
// 131.677 us; speedup vs baseline: 1.1329x; 1.1329x over previous
//
#include <hip/hip_runtime.h>
#include <math.h>

#define NPROP 2048
#define NCLS 81
#define NFG 80
#define CAP 512        // per-class candidate cap (mean ~59, huge margin)
#define TOPC 100       // per-class survivors that can matter for global top-100
#define CPAD 16        // ints per counter (64B cacheline padding)
#define NB 1152        // score histogram buckets
#define BMIN 0x7A99    // bits(0.05f) >> 15

// ws layout:
//   ccnt : int[80*16]   @ 0       (5120 B, zeroed via memsetAsync)
//   scnt : int[80]      @ 5120    (fully written by nms_kernel)
//   cand : ull[80*512]  @ 5440
//   surv : ull[80*100]  @ 333120  DENSE, stride TOPC   (end 397120)

#define LDS_FENCE() do { __builtin_amdgcn_wave_barrier(); \
    asm volatile("s_waitcnt lgkmcnt(0)" ::: "memory");     \
    __builtin_amdgcn_wave_barrier(); } while (0)

__device__ __forceinline__ void decode_clip(const float* __restrict__ props,
                                            const float* __restrict__ reg,
                                            int p, int cls, float out[4]) {
    float px1 = props[p * 4 + 0], py1 = props[p * 4 + 1];
    float px2 = props[p * 4 + 2], py2 = props[p * 4 + 3];
    float w = px2 - px1 + 1.0f;
    float h = py2 - py1 + 1.0f;
    float cx = px1 + 0.5f * w;
    float cy = py1 + 0.5f * h;
    const float* r = reg + (size_t)p * (NCLS * 4) + cls * 4;
    float dx = r[0] / 10.0f;
    float dy = r[1] / 10.0f;
    float dw = fminf(r[2] / 5.0f, 4.135166556742356f);
    float dh = fminf(r[3] / 5.0f, 4.135166556742356f);
    float pcx = dx * w + cx;
    float pcy = dy * h + cy;
    float pw = expf(dw) * w;
    float ph = expf(dh) * h;
    float x1 = pcx - 0.5f * pw;
    float y1 = pcy - 0.5f * ph;
    float x2 = pcx + 0.5f * pw - 1.0f;
    float y2 = pcy + 0.5f * ph - 1.0f;
    out[0] = fminf(fmaxf(x1, 0.0f), 1332.0f);
    out[1] = fminf(fmaxf(y1, 0.0f), 799.0f);
    out[2] = fminf(fmaxf(x2, 0.0f), 1332.0f);
    out[3] = fminf(fmaxf(y2, 0.0f), 799.0f);
}

// one wave per proposal row: softmax in registers, scatter valid (score>0.05)
// candidates into per-class segments (counters padded to one cacheline each).
__global__ __launch_bounds__(256) void softmax_scatter(const float* __restrict__ logits,
                                                       int* __restrict__ ccnt,
                                                       unsigned long long* __restrict__ cand) {
    int gw = (blockIdx.x * blockDim.x + threadIdx.x) >> 6;
    int lane = threadIdx.x & 63;
    if (gw >= NPROP) return;
    const float* row = logits + (size_t)gw * NCLS;
    float a = row[lane];                       // lane < 64 < 81
    bool hasb = (lane + 64) < NCLS;            // lanes 0..16
    float b = hasb ? row[lane + 64] : -INFINITY;
    float m = fmaxf(a, b);
    #pragma unroll
    for (int s = 32; s; s >>= 1) m = fmaxf(m, __shfl_xor(m, s));
    float ea = expf(a - m);
    float eb = hasb ? expf(b - m) : 0.0f;
    float sum = ea + eb;
    #pragma unroll
    for (int s = 32; s; s >>= 1) sum += __shfl_xor(sum, s);
    float pa = ea / sum;
    float pb = eb / sum;
    unsigned int np = (unsigned int)(~gw);
    if (lane != 0 && pa > 0.05f) {             // skip background class 0
        int c = lane - 1;
        int pos = atomicAdd(&ccnt[c * CPAD], 1);
        if (pos < CAP)
            cand[c * CAP + pos] =
                ((unsigned long long)__float_as_uint(pa) << 32) | np;
    }
    if (hasb && pb > 0.05f) {                  // classes 64..80 -> c = 63..79
        int c = lane + 63;
        int pos = atomicAdd(&ccnt[c * CPAD], 1);
        if (pos < CAP)
            cand[c * CAP + pos] =
                ((unsigned long long)__float_as_uint(pb) << 32) | np;
    }
}

// ONE WAVE per foreground class: wave-synchronous sort + register-resident
// greedy NMS (no __syncthreads). Survivors written DENSE (stride TOPC).
__global__ __launch_bounds__(64) void nms_kernel(const int* __restrict__ ccnt,
                                                 const unsigned long long* __restrict__ cand,
                                                 const float* __restrict__ props,
                                                 const float* __restrict__ reg,
                                                 int* __restrict__ scnt,
                                                 unsigned long long* __restrict__ surv) {
    const int c = blockIdx.x;
    const int lane = threadIdx.x;
    __shared__ unsigned long long keys[CAP];
    __shared__ float4 bx[CAP];
    int M = ccnt[c * CPAD];
    if (M > CAP) M = CAP;
    if (M == 0) { if (lane == 0) scnt[c] = 0; return; }
    int S = 64;
    while (S < M) S <<= 1;

    for (int i = lane; i < S; i += 64)
        keys[i] = (i < M) ? cand[c * CAP + i] : 0ULL;
    LDS_FENCE();

    // wave-synchronous bitonic sort descending (zero pads sink to back)
    for (int k = 2; k <= S; k <<= 1) {
        for (int j = k >> 1; j > 0; j >>= 1) {
            for (int i = lane; i < S; i += 64) {
                int l = i ^ j;
                if (l > i) {
                    unsigned long long A = keys[i], B = keys[l];
                    bool dir = ((i & k) == 0);
                    if ((A < B) == dir) { keys[i] = B; keys[l] = A; }
                }
            }
            LDS_FENCE();
        }
    }

    // decode boxes: own slots to registers, all to LDS for broadcast
    float4 myb[8];
    #pragma unroll
    for (int ns = 0; ns < 8; ++ns) {
        int idx = lane + ns * 64;
        if (idx < M) {
            unsigned long long key = keys[idx];
            int p = (int)(~(unsigned int)key);
            float b4[4];
            decode_clip(props, reg, p, c + 1, b4);
            float4 f = make_float4(b4[0], b4[1], b4[2], b4[3]);
            myb[ns] = f;
            bx[idx] = f;
        }
    }
    LDS_FENCE();

    // greedy NMS: sequential i, suppression mask in registers (bit ns = slot)
    unsigned int my_sup = 0u;
    for (int i = 0; i < M; ++i) {
        int owner = i & 63, slot = i >> 6;
        unsigned int os = __shfl(my_sup, owner);
        if ((os >> slot) & 1u) continue;       // wave-uniform
        float4 bi = bx[i];                     // broadcast LDS read
        float ai = (bi.z - bi.x + 1.0f) * (bi.w - bi.y + 1.0f);
        #pragma unroll
        for (int ns = 0; ns < 8; ++ns) {
            int j = lane + ns * 64;
            if (j < M && j > i) {
                float4 bj = myb[ns];
                float aj = (bj.z - bj.x + 1.0f) * (bj.w - bj.y + 1.0f);
                float ltx = fmaxf(bi.x, bj.x), lty = fmaxf(bi.y, bj.y);
                float rbx = fminf(bi.z, bj.z), rby = fminf(bi.w, bj.w);
                float iw = fmaxf(rbx - ltx + 1.0f, 0.0f);
                float ih = fmaxf(rby - lty + 1.0f, 0.0f);
                float inter = iw * ih;
                float iou = inter / (ai + aj - inter);
                if (iou > 0.5f) my_sup |= (1u << ns);
            }
        }
    }

    // ballot-compact survivors (descending order), re-key with ~flat;
    // only the first TOPC per class can matter globally -> dense stride TOPC.
    int base = 0;
    #pragma unroll
    for (int ns = 0; ns < 8; ++ns) {
        if (ns * 64 >= M) break;               // uniform
        int j = lane + ns * 64;
        bool keep = (j < M) && !((my_sup >> ns) & 1u);
        unsigned long long mask = __ballot(keep);
        if (keep) {
            int pos = base + __popcll(mask & ((1ULL << lane) - 1ULL));
            if (pos < TOPC) {
                unsigned long long key = keys[j];
                int p = (int)(~(unsigned int)key);
                unsigned int flat = (unsigned int)(c * NPROP + p);
                surv[c * TOPC + pos] =
                    (key & 0xFFFFFFFF00000000ULL) | (unsigned int)(~flat);
            }
        }
        base += __popcll(mask);
    }
    if (lane == 0) scnt[c] = base;
}

// single block: radix-select threshold bucket over the dense 64KB survivor
// block, compact ~K>=100 candidates, wave-synchronous sort, emit top-100.
__global__ __launch_bounds__(256) void topk_kernel(const int* __restrict__ scnt,
                                                   const unsigned long long* __restrict__ surv,
                                                   const float* __restrict__ props,
                                                   const float* __restrict__ reg,
                                                   float* __restrict__ out) {
    __shared__ unsigned int hist[NB];
    __shared__ unsigned long long comp[1024];
    __shared__ int s_n[NFG];
    __shared__ int sB;
    __shared__ int compN;
    const int tid = threadIdx.x;

    for (int i = tid; i < NB; i += 256) hist[i] = 0u;
    if (tid < NFG) {
        int k = scnt[tid];
        s_n[tid] = (k > TOPC) ? TOPC : k;
    }
    if (tid == 0) compN = 0;
    __syncthreads();

    // histogram of score high bits (dense reads, fully pipelined)
    for (int idx = tid; idx < NFG * TOPC; idx += 256) {
        int cc = idx / TOPC, i = idx - cc * TOPC;
        if (i < s_n[cc]) {
            unsigned long long key = surv[idx];
            int b = (int)(((unsigned int)(key >> 32)) >> 15) - BMIN;
            b = b < 0 ? 0 : (b >= NB ? NB - 1 : b);
            atomicAdd(&hist[b], 1u);
        }
    }
    __syncthreads();

    // wave 0: suffix-sum from top to find threshold bucket (cum >= 100)
    if (tid < 64) {
        int running = 0, Bstar = 0;
        bool found = false;
        for (int chunk = NB - 64; chunk >= 0; chunk -= 64) {
            int b = chunk + 63 - tid;              // lane 0 = highest bucket
            int s = (int)hist[b];
            #pragma unroll
            for (int d = 1; d < 64; d <<= 1) {
                int o = __shfl_up(s, d);
                if (tid >= d) s += o;
            }
            int cum = running + s;
            unsigned long long m = __ballot(cum >= TOPC);
            if (m != 0ULL) {
                int l = (int)__ffsll((unsigned long long)m) - 1;
                Bstar = chunk + 63 - l;
                found = true;
                break;
            }
            running += __shfl(s, 63);
        }
        if (!found) Bstar = 0;
        if (tid == 0) sB = Bstar;
    }
    __syncthreads();
    int Bstar = sB;

    // compact candidates with bucket >= Bstar (second pass is L2-hot)
    for (int idx = tid; idx < NFG * TOPC; idx += 256) {
        int cc = idx / TOPC, i = idx - cc * TOPC;
        if (i < s_n[cc]) {
            unsigned long long key = surv[idx];
            int b = (int)(((unsigned int)(key >> 32)) >> 15) - BMIN;
            b = b < 0 ? 0 : (b >= NB ? NB - 1 : b);
            if (b >= Bstar) {
                int pos = atomicAdd(&compN, 1);
                if (pos < 1024) comp[pos] = key;
            }
        }
    }
    __syncthreads();
    int K = compN;
    if (K > 1024) K = 1024;
    int P = 128;
    while (P < K) P <<= 1;
    for (int i = K + tid; i < P; i += 256) comp[i] = 0ULL;
    __syncthreads();

    // wave 0: wave-synchronous bitonic sort descending over comp[0..P)
    if (tid < 64) {
        for (int k = 2; k <= P; k <<= 1) {
            for (int j = k >> 1; j > 0; j >>= 1) {
                for (int i = tid; i < P; i += 64) {
                    int l = i ^ j;
                    if (l > i) {
                        unsigned long long A = comp[i], B = comp[l];
                        bool dir = ((i & k) == 0);
                        if ((A < B) == dir) { comp[i] = B; comp[l] = A; }
                    }
                }
                LDS_FENCE();
            }
        }
    }
    __syncthreads();

    if (tid < TOPC) {
        unsigned long long key = comp[tid];
        float score;
        int flat;
        if (key == 0ULL) {             // < 100 total survivors: not expected
            score = -1.0f;
            flat = tid;
        } else {
            score = __uint_as_float((unsigned int)(key >> 32));
            flat = (int)(~(unsigned int)key);
        }
        int cc = flat >> 11;           // NPROP = 2^11
        int p = flat & (NPROP - 1);
        float b4[4];
        decode_clip(props, reg, p, cc + 1, b4);
        out[tid * 4 + 0] = b4[0];
        out[tid * 4 + 1] = b4[1];
        out[tid * 4 + 2] = b4[2];
        out[tid * 4 + 3] = b4[3];
        out[400 + tid] = score;
        out[500 + tid] = (float)(cc + 1);
    }
}

extern "C" void kernel_launch(void* const* d_in, const int* in_sizes, int n_in,
                              void* d_out, int out_size, void* d_ws, size_t ws_size,
                              hipStream_t stream) {
    const float* logits = (const float*)d_in[0];
    const float* reg    = (const float*)d_in[1];
    const float* props  = (const float*)d_in[2];
    float* out = (float*)d_out;

    int* ccnt = (int*)d_ws;
    int* scnt = (int*)((char*)d_ws + 5120);
    unsigned long long* cand = (unsigned long long*)((char*)d_ws + 5440);
    unsigned long long* surv = (unsigned long long*)((char*)d_ws + 333120);

    hipMemsetAsync(d_ws, 0, 5120, stream);
    hipLaunchKernelGGL(softmax_scatter, dim3((NPROP * 64) / 256), dim3(256), 0, stream,
                       logits, ccnt, cand);
    hipLaunchKernelGGL(nms_kernel, dim3(NFG), dim3(64), 0, stream,
                       ccnt, cand, props, reg, scnt, surv);
    hipLaunchKernelGGL(topk_kernel, dim3(1), dim3(256), 0, stream,
                       scnt, surv, props, reg, out);
}